// Round 3
// baseline (734.365 us; speedup 1.0000x reference)
//
#include <hip/hip_runtime.h>

#define NN    60000
#define NODES 100000
#define DD    64
#define NNZ   3200000
#define BB    1024
#define NEG   0.2f
#define RPB   196                        // rows per bucket
#define NBUCK 511                        // ceil(NODES/RPB)
#define EPB   8192                       // edges per sort block
#define NPB   ((NNZ + EPB - 1) / EPB)    // 391
#define CAP   7000                       // bucket capacity (mean 6272, sd~79)
#define BCAP  7168                       // LDS edge capacity in k_csr
#define NSEG  13                         // column segments (col>>13), ~2 MB x-slice each
#define KEYN  (NSEG * RPB)               // 2548 sort keys per bucket
#define SPB   (KEYN + 1)                 // starts entries per bucket
#define ESEG  1792                       // per-seg LDS edge cap (mean 514, ~56 sigma)
#define BLK   16                         // edges per pipeline block

// ---------------------------------------------------------------- init x = concat(eu, ei); also init gcur
__global__ __launch_bounds__(256) void k_init_x(const float* __restrict__ eu,
                                                const float* __restrict__ ei,
                                                float* __restrict__ x,
                                                int* __restrict__ gcur) {
    int i = blockIdx.x * 256 + threadIdx.x;          // float4 index
    if (i < NBUCK) gcur[i] = i * CAP;
    const int TOT = NODES * DD / 4;
    if (i >= TOT) return;
    const int UE = NN * DD / 4;
    float4 v = (i < UE) ? ((const float4*)eu)[i] : ((const float4*)ei)[i - UE];
    ((float4*)x)[i] = v;
}

// ---------------------------------------------------------------- bucket sort -> bulk
__global__ __launch_bounds__(512) void k_place(const int* __restrict__ row,
                                               const int* __restrict__ col,
                                               const float* __restrict__ val,
                                               int* __restrict__ gcur,
                                               int2* __restrict__ bulk) {
    __shared__ int rows_l[EPB];                // 32 KB
    __shared__ unsigned short perm[EPB];       // 16 KB
    __shared__ int h[NBUCK], bloc[NBUCK], bcur[NBUCK], gseg[NBUCK];
    __shared__ int sc[512];
    int t = threadIdx.x;
    if (t < NBUCK) h[t] = 0;
    __syncthreads();
    int base = blockIdx.x * EPB;
    int n = min(EPB, NNZ - base);
    for (int k = t; k < n; k += 512) {
        int r = row[base + k];
        rows_l[k] = r;
        atomicAdd(&h[r / RPB], 1);
    }
    __syncthreads();
    {
        int v = (t < NBUCK) ? h[t] : 0;
        sc[t] = v;
        __syncthreads();
        for (int off = 1; off < 512; off <<= 1) {
            int u = (t >= off) ? sc[t - off] : 0;
            __syncthreads();
            sc[t] += u;
            __syncthreads();
        }
        if (t < NBUCK) {
            int ex = sc[t] - v;
            bloc[t] = ex;
            bcur[t] = ex;
            gseg[t] = v ? atomicAdd(&gcur[t], v) : 0;
        }
    }
    __syncthreads();
    for (int k = t; k < n; k += 512) {
        int p = atomicAdd(&bcur[rows_l[k] / RPB], 1);
        perm[p] = (unsigned short)k;
    }
    __syncthreads();
    for (int j = t; j < n; j += 512) {
        int k = perm[j];
        int r = rows_l[k];
        int b = r / RPB;
        int addr = gseg[b] + (j - bloc[b]);
        bulk[addr] = make_int2(((r - b * RPB) << 17) | col[base + k],
                               __float_as_int(val[base + k]));
    }
}

// ---------------------------------------------------------------- per-bucket (colseg,row) sort
// in-place (keeps packed local-row bits); emit per-key span starts + sentinel
__global__ __launch_bounds__(512) void k_csr(const int* __restrict__ gcur,
                                             int2* __restrict__ bulk,
                                             int* __restrict__ starts) {
    __shared__ int2 eds[BCAP];                 // 56 KB
    __shared__ int cnt[KEYN], pos[KEYN];       // 20 KB
    __shared__ int part[512];
    int b = blockIdx.x, t = threadIdx.x;
    int lo = b * CAP;
    int n = gcur[b] - lo;
    for (int k = t; k < KEYN; k += 512) cnt[k] = 0;
    __syncthreads();
    for (int i = t; i < n; i += 512) {
        int2 ed = bulk[lo + i];
        eds[i] = ed;
        int lr = ed.x >> 17, c = ed.x & 0x1FFFF;
        atomicAdd(&cnt[(c >> 13) * RPB + lr], 1);
    }
    __syncthreads();
    // two-level exclusive scan over KEYN bins (5 bins/thread)
    int run = 0;
#pragma unroll
    for (int j = 0; j < 5; ++j) {
        int k = t * 5 + j;
        if (k < KEYN) { pos[k] = run; run += cnt[k]; }
    }
    part[t] = run;
    __syncthreads();
    for (int off = 1; off < 512; off <<= 1) {
        int u = (t >= off) ? part[t - off] : 0;
        __syncthreads();
        part[t] += u;
        __syncthreads();
    }
    int poff = part[t] - run;
#pragma unroll
    for (int j = 0; j < 5; ++j) {
        int k = t * 5 + j;
        if (k < KEYN) pos[k] += poff;
    }
    __syncthreads();
    for (int k = t; k < KEYN; k += 512) {
        starts[b * SPB + k] = lo + pos[k];
        cnt[k] = pos[k];                      // reuse as cursor
    }
    if (t == 0) starts[b * SPB + KEYN] = lo + n;
    __syncthreads();
    for (int i = t; i < n; i += 512) {
        int2 ed = eds[i];
        int lr = ed.x >> 17, c = ed.x & 0x1FFFF;
        int p = atomicAdd(&cnt[(c >> 13) * RPB + lr], 1);
        bulk[lo + p] = ed;                    // keep packed (lr<<17 | col)
    }
}

// ---------------------------------------------------------------- convoyed seg-major pull SpMM
// V4: per-seg LDS edge staging (double-buffered, issue-early/write-late).
// Edge reads are ds_read_b64 at wave-uniform addresses (lgkmcnt) -> independent
// of the x-gather vmcnt pipe, so gathers stay 16-32 deep in flight.
// readfirstlane -> scalar col/row -> saddr gathers + scalar row-change branch.
// Edges hit HBM exactly once, coalesced (fixes round-2's 2x FETCH).
__global__ __launch_bounds__(1024) void k_cspmm(const int* __restrict__ starts,
                                                const int2* __restrict__ cv,
                                                const float* __restrict__ x,
                                                float* __restrict__ lie) {
    __shared__ float acc[RPB * DD];            // 50176 B
    __shared__ int2 eb[2][ESEG];               // 28672 B  (total 78848 -> 2 blocks/CU)
    int t = threadIdx.x, b = blockIdx.x;
    float4* av = (float4*)acc;
    for (int i = t; i < RPB * 16; i += 1024) av[i] = make_float4(0.f, 0.f, 0.f, 0.f);
    int lane = t & 63;
    int wid = __builtin_amdgcn_readfirstlane(t >> 6);   // wave-uniform
    int r0 = (wid * RPB) >> 4;
    int r1 = ((wid + 1) * RPB) >> 4;
    int sb = b * SPB;

    // prologue: stage seg 0 into eb[0]
    {
        int g0 = starts[sb];
        int g1 = starts[sb + RPB];
        int n0 = g1 - g0; if (n0 > ESEG) n0 = ESEG;
        for (int i = t; i < n0; i += 1024) eb[0][i] = cv[g0 + i];
    }
    __syncthreads();

    for (int seg = 0; seg < NSEG; ++seg) {
        // issue next-seg staging loads into regs (latency hides under compute)
        int nn = 0; int2 stgA, stgB;
        if (seg + 1 < NSEG) {
            int s1 = starts[sb + (seg + 1) * RPB];
            int e1 = starts[sb + (seg + 2) * RPB];   // seg+2==NSEG -> sentinel
            nn = e1 - s1; if (nn > ESEG) nn = ESEG;
            if (t < nn) stgA = cv[s1 + t];
            if (t + 1024 < nn) stgB = cv[s1 + t + 1024];
        }
        // compute this seg from eb[seg&1]
        const int2* ep = eb[seg & 1];
        int segb = starts[sb + seg * RPB];
        int sA = starts[sb + seg * RPB + r0] - segb;
        int eA = starts[sb + seg * RPB + r1] - segb;  // r1==RPB -> next segbase
        if (eA > ESEG) eA = ESEG;
        if (sA > eA) sA = eA;
        if (sA < eA) {
            int cur = -1; float f = 0.f;
            int sx0[BLK], sx1[BLK];
            float vv0[BLK], vv1[BLK], xg0[BLK], xg1[BLK];
            int i = sA;
#define LOADB(S, base_) { \
    _Pragma("unroll") \
    for (int j = 0; j < BLK; ++j) { \
        int idx = (base_) + j; \
        int idc = idx < eA ? idx : eA - 1; \
        int2 ed = ep[idc]; \
        int ex = __builtin_amdgcn_readfirstlane(ed.x); \
        int ey = __builtin_amdgcn_readfirstlane(ed.y); \
        sx##S[j] = ex; \
        vv##S[j] = (idx < eA) ? __int_as_float(ey) : 0.f; \
        xg##S[j] = x[(ex & 0x1FFFF) * DD + lane]; \
    } }
#define CONSB(S) { \
    _Pragma("unroll") \
    for (int j = 0; j < BLK; ++j) { \
        int r = ((unsigned)sx##S[j]) >> 17; \
        if (r != cur) { if (cur >= 0) acc[cur * DD + lane] += f; cur = r; f = 0.f; } \
        f = fmaf(vv##S[j], xg##S[j], f); \
    } }
            LOADB(0, i)
            for (;;) {
                if (i + BLK < eA) { LOADB(1, i + BLK) CONSB(0) i += BLK; }
                else             { CONSB(0) break; }
                if (i + BLK < eA) { LOADB(0, i + BLK) CONSB(1) i += BLK; }
                else             { CONSB(1) break; }
            }
            if (cur >= 0) acc[cur * DD + lane] += f;
#undef LOADB
#undef CONSB
        }
        __syncthreads();                       // all waves done reading eb[seg&1 ^1] (seg-1)
        if (t < nn) eb[(seg & 1) ^ 1][t] = stgA;
        if (t + 1024 < nn) eb[(seg & 1) ^ 1][t + 1024] = stgB;
        __syncthreads();                       // next seg's buffer ready
    }
    __syncthreads();
    int row0 = b * RPB;
    for (int i = t; i < RPB * 16; i += 1024) {
        int gr = row0 + (i >> 4);
        if (gr < NODES) ((float4*)lie)[gr * 16 + (i & 15)] = av[i];
    }
}

// ---------------------------------------------------------------- fused layer GEMM
__global__ __launch_bounds__(256) void k_gemm(float* __restrict__ x,
                                              const float* __restrict__ lie,
                                              const float* __restrict__ W1,
                                              const float* __restrict__ W2,
                                              const float* __restrict__ b1,
                                              const float* __restrict__ b2) {
    __shared__ float A1[64 * 64];
    __shared__ float A2[64 * 64];
    __shared__ float Ws1[64 * 64];
    __shared__ float Ws2[64 * 64];

    const int t = threadIdx.x;
    const int row0 = blockIdx.x * 64;

    {
        const float4* w1v = (const float4*)W1;
        const float4* w2v = (const float4*)W2;
        float4* s1v = (float4*)Ws1;
        float4* s2v = (float4*)Ws2;
#pragma unroll
        for (int q = 0; q < 4; ++q) {
            s1v[q * 256 + t] = w1v[q * 256 + t];
            s2v[q * 256 + t] = w2v[q * 256 + t];
        }
    }
#pragma unroll
    for (int q = 0; q < 4; ++q) {
        int f4 = q * 256 + t;
        int rl = f4 >> 4;
        int c4 = f4 & 15;
        int gr = row0 + rl;
        float4 lv = make_float4(0.f, 0.f, 0.f, 0.f);
        float4 xv = make_float4(0.f, 0.f, 0.f, 0.f);
        if (gr < NODES) {
            lv = *(const float4*)&lie[gr * DD + c4 * 4];
            xv = *(const float4*)&x[gr * DD + c4 * 4];
        }
        int sg = c4 ^ (rl & 15);
        ((float4*)A1)[rl * 16 + sg] = lv;
        ((float4*)A2)[rl * 16 + sg] = make_float4(lv.x * xv.x, lv.y * xv.y,
                                                  lv.z * xv.z, lv.w * xv.w);
    }
    __syncthreads();

    const int tx = t & 15;
    const int ty = t >> 4;
    float bs[4];
    {
        float4 bb1 = *(const float4*)&b1[tx * 4];
        float4 bb2 = *(const float4*)&b2[tx * 4];
        bs[0] = bb1.x + bb2.x; bs[1] = bb1.y + bb2.y;
        bs[2] = bb1.z + bb2.z; bs[3] = bb1.w + bb2.w;
    }
    float acc[4][4];
#pragma unroll
    for (int i = 0; i < 4; ++i)
#pragma unroll
        for (int j = 0; j < 4; ++j) acc[i][j] = bs[j];

    for (int k4 = 0; k4 < 16; ++k4) {
        float4 a1[4], a2[4];
#pragma unroll
        for (int i = 0; i < 4; ++i) {
            int r = ty * 4 + i;
            int sg = k4 ^ (r & 15);
            a1[i] = ((const float4*)A1)[r * 16 + sg];
            a2[i] = ((const float4*)A2)[r * 16 + sg];
        }
#pragma unroll
        for (int kk = 0; kk < 4; ++kk) {
            float4 w1 = ((const float4*)Ws1)[(k4 * 4 + kk) * 16 + tx];
            float4 w2 = ((const float4*)Ws2)[(k4 * 4 + kk) * 16 + tx];
#pragma unroll
            for (int i = 0; i < 4; ++i) {
                float av1 = (&a1[i].x)[kk];
                float av2 = (&a2[i].x)[kk];
                acc[i][0] = fmaf(av1, w1.x, fmaf(av2, w2.x, acc[i][0]));
                acc[i][1] = fmaf(av1, w1.y, fmaf(av2, w2.y, acc[i][1]));
                acc[i][2] = fmaf(av1, w1.z, fmaf(av2, w2.z, acc[i][2]));
                acc[i][3] = fmaf(av1, w1.w, fmaf(av2, w2.w, acc[i][3]));
            }
        }
    }
#pragma unroll
    for (int i = 0; i < 4; ++i) {
        int gr = row0 + ty * 4 + i;
        if (gr < NODES) {
            float4 o;
            o.x = acc[i][0] >= 0.f ? acc[i][0] : NEG * acc[i][0];
            o.y = acc[i][1] >= 0.f ? acc[i][1] : NEG * acc[i][1];
            o.z = acc[i][2] >= 0.f ? acc[i][2] : NEG * acc[i][2];
            o.w = acc[i][3] >= 0.f ? acc[i][3] : NEG * acc[i][3];
            *(float4*)&x[gr * DD + tx * 4] = o;
        }
    }
}

// ---------------------------------------------------------------- gather layer repr into output
__global__ __launch_bounds__(256) void k_gather(const float* __restrict__ x,
                                                const int* __restrict__ su,
                                                const int* __restrict__ oi,
                                                const int* __restrict__ ui,
                                                float* __restrict__ out, int layer) {
    int w    = (blockIdx.x * 256 + threadIdx.x) >> 6;
    int lane = threadIdx.x & 63;
    if (w >= 3 * BB) return;
    int g = w >> 10, b = w & 1023;
    int node = (g == 0) ? su[b] : (NN + ((g == 1) ? oi[b] : ui[b]));
    out[w * 256 + layer * 64 + lane] = x[node * DD + lane];
}

// ---------------------------------------------------------------- launch
extern "C" void kernel_launch(void* const* d_in, const int* in_sizes, int n_in,
                              void* d_out, int out_size, void* d_ws, size_t ws_size,
                              hipStream_t stream) {
    const int*   edge_row = (const int*)d_in[0];
    const int*   edge_col = (const int*)d_in[1];
    const float* edge_val = (const float*)d_in[2];
    const float* eu = (const float*)d_in[3];
    const float* ei = (const float*)d_in[4];
    const float* W1 = (const float*)d_in[5];
    const float* W2 = (const float*)d_in[6];
    const float* b1 = (const float*)d_in[7];
    const float* b2 = (const float*)d_in[8];
    const int*   su = (const int*)d_in[9];
    const int*   oi = (const int*)d_in[10];
    const int*   ui = (const int*)d_in[11];
    float* out = (float*)d_out;

    // workspace carve (~85 MB)
    float* x      = (float*)d_ws;                    // 25.6 MB
    float* lie    = x + NODES * DD;                  // 25.6 MB
    int2*  bulk   = (int2*)(lie + NODES * DD);       // NBUCK*CAP int2 (28.6 MB)
    int*   gcur   = (int*)(bulk + NBUCK * CAP);      // NBUCK
    int*   starts = gcur + NBUCK + 1;                // NBUCK*SPB (5.2 MB)

    k_init_x<<<(NODES * DD / 4 + 255) / 256, 256, 0, stream>>>(eu, ei, x, gcur);
    k_gather<<<(3 * BB * 64 + 255) / 256, 256, 0, stream>>>(x, su, oi, ui, out, 0);

    k_place<<<NPB, 512, 0, stream>>>(edge_row, edge_col, edge_val, gcur, bulk);
    k_csr<<<NBUCK, 512, 0, stream>>>(gcur, bulk, starts);

    for (int l = 0; l < 3; ++l) {
        k_cspmm<<<NBUCK, 1024, 0, stream>>>(starts, bulk, x, lie);
        k_gemm<<<(NODES + 63) / 64, 256, 0, stream>>>(x, lie,
                                                      W1 + l * 4096, W2 + l * 4096,
                                                      b1 + l * 64,  b2 + l * 64);
        k_gather<<<(3 * BB * 64 + 255) / 256, 256, 0, stream>>>(x, su, oi, ui, out, l + 1);
    }
}

// Round 4
// 624.345 us; speedup vs baseline: 1.1762x; 1.1762x over previous
//
#include <hip/hip_runtime.h>

#define NN    60000
#define NODES 100000
#define DD    64
#define NNZ   3200000
#define BB    1024
#define NEG   0.2f
#define RPB   196                        // rows per bucket
#define NBUCK 511                        // ceil(NODES/RPB)
#define EPB   8192                       // edges per sort block
#define NPB   ((NNZ + EPB - 1) / EPB)    // 391
#define CAP   7000                       // bucket capacity (mean 6272, sd~79)
#define BCAP  7168                       // LDS edge capacity in k_csr
#define NSEG  13                         // column segments (col>>13), ~2 MB x-slice each
#define KEYN  (NSEG * RPB)               // 2548 sort keys per bucket
#define SPB   (KEYN + 1)                 // starts entries per bucket

// ---------------------------------------------------------------- init x = concat(eu, ei); also init gcur
__global__ __launch_bounds__(256) void k_init_x(const float* __restrict__ eu,
                                                const float* __restrict__ ei,
                                                float* __restrict__ x,
                                                int* __restrict__ gcur) {
    int i = blockIdx.x * 256 + threadIdx.x;          // float4 index
    if (i < NBUCK) gcur[i] = i * CAP;
    const int TOT = NODES * DD / 4;
    if (i >= TOT) return;
    const int UE = NN * DD / 4;
    float4 v = (i < UE) ? ((const float4*)eu)[i] : ((const float4*)ei)[i - UE];
    ((float4*)x)[i] = v;
}

// ---------------------------------------------------------------- bucket sort -> bulk
__global__ __launch_bounds__(512) void k_place(const int* __restrict__ row,
                                               const int* __restrict__ col,
                                               const float* __restrict__ val,
                                               int* __restrict__ gcur,
                                               int2* __restrict__ bulk) {
    __shared__ int rows_l[EPB];                // 32 KB
    __shared__ unsigned short perm[EPB];       // 16 KB
    __shared__ int h[NBUCK], bloc[NBUCK], bcur[NBUCK], gseg[NBUCK];
    __shared__ int sc[512];
    int t = threadIdx.x;
    if (t < NBUCK) h[t] = 0;
    __syncthreads();
    int base = blockIdx.x * EPB;
    int n = min(EPB, NNZ - base);
    for (int k = t; k < n; k += 512) {
        int r = row[base + k];
        rows_l[k] = r;
        atomicAdd(&h[r / RPB], 1);
    }
    __syncthreads();
    {
        int v = (t < NBUCK) ? h[t] : 0;
        sc[t] = v;
        __syncthreads();
        for (int off = 1; off < 512; off <<= 1) {
            int u = (t >= off) ? sc[t - off] : 0;
            __syncthreads();
            sc[t] += u;
            __syncthreads();
        }
        if (t < NBUCK) {
            int ex = sc[t] - v;
            bloc[t] = ex;
            bcur[t] = ex;
            gseg[t] = v ? atomicAdd(&gcur[t], v) : 0;
        }
    }
    __syncthreads();
    for (int k = t; k < n; k += 512) {
        int p = atomicAdd(&bcur[rows_l[k] / RPB], 1);
        perm[p] = (unsigned short)k;
    }
    __syncthreads();
    for (int j = t; j < n; j += 512) {
        int k = perm[j];
        int r = rows_l[k];
        int b = r / RPB;
        int addr = gseg[b] + (j - bloc[b]);
        bulk[addr] = make_int2(((r - b * RPB) << 17) | col[base + k],
                               __float_as_int(val[base + k]));
    }
}

// ---------------------------------------------------------------- per-bucket (colseg,row) sort
// in-place (keeps packed local-row bits); emit per-key span starts + sentinel
__global__ __launch_bounds__(512) void k_csr(const int* __restrict__ gcur,
                                             int2* __restrict__ bulk,
                                             int* __restrict__ starts) {
    __shared__ int2 eds[BCAP];                 // 56 KB
    __shared__ int cnt[KEYN], pos[KEYN];       // 20 KB
    __shared__ int part[512];
    int b = blockIdx.x, t = threadIdx.x;
    int lo = b * CAP;
    int n = gcur[b] - lo;
    for (int k = t; k < KEYN; k += 512) cnt[k] = 0;
    __syncthreads();
    for (int i = t; i < n; i += 512) {
        int2 ed = bulk[lo + i];
        eds[i] = ed;
        int lr = ed.x >> 17, c = ed.x & 0x1FFFF;
        atomicAdd(&cnt[(c >> 13) * RPB + lr], 1);
    }
    __syncthreads();
    // two-level exclusive scan over KEYN bins (5 bins/thread)
    int run = 0;
#pragma unroll
    for (int j = 0; j < 5; ++j) {
        int k = t * 5 + j;
        if (k < KEYN) { pos[k] = run; run += cnt[k]; }
    }
    part[t] = run;
    __syncthreads();
    for (int off = 1; off < 512; off <<= 1) {
        int u = (t >= off) ? part[t - off] : 0;
        __syncthreads();
        part[t] += u;
        __syncthreads();
    }
    int poff = part[t] - run;
#pragma unroll
    for (int j = 0; j < 5; ++j) {
        int k = t * 5 + j;
        if (k < KEYN) pos[k] += poff;
    }
    __syncthreads();
    for (int k = t; k < KEYN; k += 512) {
        starts[b * SPB + k] = lo + pos[k];
        cnt[k] = pos[k];                      // reuse as cursor
    }
    if (t == 0) starts[b * SPB + KEYN] = lo + n;
    __syncthreads();
    for (int i = t; i < n; i += 512) {
        int2 ed = eds[i];
        int lr = ed.x >> 17, c = ed.x & 0x1FFFF;
        int p = atomicAdd(&cnt[(c >> 13) * RPB + lr], 1);
        bulk[lo + p] = ed;                    // keep packed (lr<<17 | col)
    }
}

// ---------------------------------------------------------------- convoyed seg-major pull SpMM
// V2: 16 lanes cooperatively fetch 16 edges; v_readlane broadcasts to SGPRs;
//     16 gathers issue back-to-back before any fma (measured ~62 us in R1).
// V5: V2 + 2-deep counted-wait pipeline: metadata(k+2) load issued BEFORE
//     readlane(k+1); gathers(k+1) issued BEFORE fma(k). In-order vmcnt then
//     resolves each wait at ~17 outstanding ops instead of draining to 0.
template <int V>
__global__ __launch_bounds__(1024) void k_cspmm(const int* __restrict__ starts,
                                                const int2* __restrict__ cv,
                                                const float* __restrict__ x,
                                                float* __restrict__ lie) {
    __shared__ float acc[RPB * DD];            // 49 KB
    int t = threadIdx.x, b = blockIdx.x;
    float4* av = (float4*)acc;
    for (int i = t; i < RPB * 16; i += 1024) av[i] = make_float4(0.f, 0.f, 0.f, 0.f);
    __syncthreads();
    int lane = t & 63;
    int wid = __builtin_amdgcn_readfirstlane(t >> 6);   // wave-uniform
    int r0 = (wid * RPB) >> 4;
    int r1 = ((wid + 1) * RPB) >> 4;
    int sb = b * SPB;
    for (int seg = 0; seg < NSEG; ++seg) {
        int s = __builtin_amdgcn_readfirstlane(starts[sb + seg * RPB + r0]);
        int e = __builtin_amdgcn_readfirstlane(starts[sb + seg * RPB + r1]);
        if (s >= e) continue;
        int cur = -1;
        float f = 0.f;
        if constexpr (V == 5) {
            int idx16 = lane & 15;
            int sxA[16], sxB[16];
            float vvA[16], vvB[16], xgA[16], xgB[16];
            int2 mA, mB;
            // prologue: M(s), M(s+16), readlane A, gathers A
            { int ia = s + idx16; if (ia >= e) ia = e - 1; mA = cv[ia]; }
            if (s + 16 < e) { int ib = s + 16 + idx16; if (ib >= e) ib = e - 1; mB = cv[ib]; }
#pragma unroll
            for (int j = 0; j < 16; ++j) {
                int ex = __builtin_amdgcn_readlane(mA.x, j);
                int ey = __builtin_amdgcn_readlane(mA.y, j);
                sxA[j] = ex;
                vvA[j] = (s + j < e) ? __int_as_float(ey) : 0.f;
                xgA[j] = x[(ex & 0x1FFFF) * DD + lane];
            }
            int i = s;
            for (;;) {
                // ---- phase A: consume batch i (in sxA/vvA/xgA); batch i+16 meta in mB
                if (i + 32 < e) { int ic = i + 32 + idx16; if (ic >= e) ic = e - 1; mA = cv[ic]; }
                bool more = (i + 16 < e);
                if (more) {
#pragma unroll
                    for (int j = 0; j < 16; ++j) {
                        int ex = __builtin_amdgcn_readlane(mB.x, j);
                        int ey = __builtin_amdgcn_readlane(mB.y, j);
                        sxB[j] = ex;
                        vvB[j] = (i + 16 + j < e) ? __int_as_float(ey) : 0.f;
                        xgB[j] = x[(ex & 0x1FFFF) * DD + lane];
                    }
                }
#pragma unroll
                for (int j = 0; j < 16; ++j) {
                    int r = ((unsigned)sxA[j]) >> 17;
                    if (r != cur) { if (cur >= 0) acc[cur * DD + lane] += f; cur = r; f = 0.f; }
                    f = fmaf(vvA[j], xgA[j], f);
                }
                i += 16;
                if (!more) break;
                // ---- phase B: consume batch i (in sxB/vvB/xgB); batch i+16 meta in mA
                if (i + 32 < e) { int ic = i + 32 + idx16; if (ic >= e) ic = e - 1; mB = cv[ic]; }
                more = (i + 16 < e);
                if (more) {
#pragma unroll
                    for (int j = 0; j < 16; ++j) {
                        int ex = __builtin_amdgcn_readlane(mA.x, j);
                        int ey = __builtin_amdgcn_readlane(mA.y, j);
                        sxA[j] = ex;
                        vvA[j] = (i + 16 + j < e) ? __int_as_float(ey) : 0.f;
                        xgA[j] = x[(ex & 0x1FFFF) * DD + lane];
                    }
                }
#pragma unroll
                for (int j = 0; j < 16; ++j) {
                    int r = ((unsigned)sxB[j]) >> 17;
                    if (r != cur) { if (cur >= 0) acc[cur * DD + lane] += f; cur = r; f = 0.f; }
                    f = fmaf(vvB[j], xgB[j], f);
                }
                i += 16;
                if (!more) break;
            }
        } else {
            // V2 (round-1 measured form)
            for (int g = s; g < e; g += 16) {
                int rem = e - g;
                if (rem > 16) rem = 16;
                int idx = lane & 15;
                if (idx >= rem) idx = rem - 1;
                int2 my = cv[g + idx];         // one dwordx2 fetches 16 edges
                if (rem == 16) {
#pragma unroll
                    for (int j = 0; j < 16; ++j) {
                        int sx = __builtin_amdgcn_readlane(my.x, j);
                        int sy = __builtin_amdgcn_readlane(my.y, j);
                        float xg = x[(sx & 0x1FFFF) * DD + lane];
                        int r = ((unsigned)sx) >> 17;
                        if (r != cur) {
                            if (cur >= 0) acc[cur * DD + lane] += f;
                            cur = r; f = 0.f;
                        }
                        f = fmaf(__int_as_float(sy), xg, f);
                    }
                } else {
                    for (int j = 0; j < rem; ++j) {
                        int sx = __builtin_amdgcn_readlane(my.x, j);
                        int sy = __builtin_amdgcn_readlane(my.y, j);
                        float xg = x[(sx & 0x1FFFF) * DD + lane];
                        int r = ((unsigned)sx) >> 17;
                        if (r != cur) {
                            if (cur >= 0) acc[cur * DD + lane] += f;
                            cur = r; f = 0.f;
                        }
                        f = fmaf(__int_as_float(sy), xg, f);
                    }
                }
            }
        }
        if (cur >= 0) acc[cur * DD + lane] += f;
    }
    __syncthreads();
    int row0 = b * RPB;
    for (int i = t; i < RPB * 16; i += 1024) {
        int gr = row0 + (i >> 4);
        if (gr < NODES) ((float4*)lie)[gr * 16 + (i & 15)] = av[i];
    }
}

// ---------------------------------------------------------------- fused layer GEMM
__global__ __launch_bounds__(256) void k_gemm(float* __restrict__ x,
                                              const float* __restrict__ lie,
                                              const float* __restrict__ W1,
                                              const float* __restrict__ W2,
                                              const float* __restrict__ b1,
                                              const float* __restrict__ b2) {
    __shared__ float A1[64 * 64];
    __shared__ float A2[64 * 64];
    __shared__ float Ws1[64 * 64];
    __shared__ float Ws2[64 * 64];

    const int t = threadIdx.x;
    const int row0 = blockIdx.x * 64;

    {
        const float4* w1v = (const float4*)W1;
        const float4* w2v = (const float4*)W2;
        float4* s1v = (float4*)Ws1;
        float4* s2v = (float4*)Ws2;
#pragma unroll
        for (int q = 0; q < 4; ++q) {
            s1v[q * 256 + t] = w1v[q * 256 + t];
            s2v[q * 256 + t] = w2v[q * 256 + t];
        }
    }
#pragma unroll
    for (int q = 0; q < 4; ++q) {
        int f4 = q * 256 + t;
        int rl = f4 >> 4;
        int c4 = f4 & 15;
        int gr = row0 + rl;
        float4 lv = make_float4(0.f, 0.f, 0.f, 0.f);
        float4 xv = make_float4(0.f, 0.f, 0.f, 0.f);
        if (gr < NODES) {
            lv = *(const float4*)&lie[gr * DD + c4 * 4];
            xv = *(const float4*)&x[gr * DD + c4 * 4];
        }
        int sg = c4 ^ (rl & 15);
        ((float4*)A1)[rl * 16 + sg] = lv;
        ((float4*)A2)[rl * 16 + sg] = make_float4(lv.x * xv.x, lv.y * xv.y,
                                                  lv.z * xv.z, lv.w * xv.w);
    }
    __syncthreads();

    const int tx = t & 15;
    const int ty = t >> 4;
    float bs[4];
    {
        float4 bb1 = *(const float4*)&b1[tx * 4];
        float4 bb2 = *(const float4*)&b2[tx * 4];
        bs[0] = bb1.x + bb2.x; bs[1] = bb1.y + bb2.y;
        bs[2] = bb1.z + bb2.z; bs[3] = bb1.w + bb2.w;
    }
    float acc[4][4];
#pragma unroll
    for (int i = 0; i < 4; ++i)
#pragma unroll
        for (int j = 0; j < 4; ++j) acc[i][j] = bs[j];

    for (int k4 = 0; k4 < 16; ++k4) {
        float4 a1[4], a2[4];
#pragma unroll
        for (int i = 0; i < 4; ++i) {
            int r = ty * 4 + i;
            int sg = k4 ^ (r & 15);
            a1[i] = ((const float4*)A1)[r * 16 + sg];
            a2[i] = ((const float4*)A2)[r * 16 + sg];
        }
#pragma unroll
        for (int kk = 0; kk < 4; ++kk) {
            float4 w1 = ((const float4*)Ws1)[(k4 * 4 + kk) * 16 + tx];
            float4 w2 = ((const float4*)Ws2)[(k4 * 4 + kk) * 16 + tx];
#pragma unroll
            for (int i = 0; i < 4; ++i) {
                float av1 = (&a1[i].x)[kk];
                float av2 = (&a2[i].x)[kk];
                acc[i][0] = fmaf(av1, w1.x, fmaf(av2, w2.x, acc[i][0]));
                acc[i][1] = fmaf(av1, w1.y, fmaf(av2, w2.y, acc[i][1]));
                acc[i][2] = fmaf(av1, w1.z, fmaf(av2, w2.z, acc[i][2]));
                acc[i][3] = fmaf(av1, w1.w, fmaf(av2, w2.w, acc[i][3]));
            }
        }
    }
#pragma unroll
    for (int i = 0; i < 4; ++i) {
        int gr = row0 + ty * 4 + i;
        if (gr < NODES) {
            float4 o;
            o.x = acc[i][0] >= 0.f ? acc[i][0] : NEG * acc[i][0];
            o.y = acc[i][1] >= 0.f ? acc[i][1] : NEG * acc[i][1];
            o.z = acc[i][2] >= 0.f ? acc[i][2] : NEG * acc[i][2];
            o.w = acc[i][3] >= 0.f ? acc[i][3] : NEG * acc[i][3];
            *(float4*)&x[gr * DD + tx * 4] = o;
        }
    }
}

// ---------------------------------------------------------------- gather layer repr into output
__global__ __launch_bounds__(256) void k_gather(const float* __restrict__ x,
                                                const int* __restrict__ su,
                                                const int* __restrict__ oi,
                                                const int* __restrict__ ui,
                                                float* __restrict__ out, int layer) {
    int w    = (blockIdx.x * 256 + threadIdx.x) >> 6;
    int lane = threadIdx.x & 63;
    if (w >= 3 * BB) return;
    int g = w >> 10, b = w & 1023;
    int node = (g == 0) ? su[b] : (NN + ((g == 1) ? oi[b] : ui[b]));
    out[w * 256 + layer * 64 + lane] = x[node * DD + lane];
}

// ---------------------------------------------------------------- launch
extern "C" void kernel_launch(void* const* d_in, const int* in_sizes, int n_in,
                              void* d_out, int out_size, void* d_ws, size_t ws_size,
                              hipStream_t stream) {
    const int*   edge_row = (const int*)d_in[0];
    const int*   edge_col = (const int*)d_in[1];
    const float* edge_val = (const float*)d_in[2];
    const float* eu = (const float*)d_in[3];
    const float* ei = (const float*)d_in[4];
    const float* W1 = (const float*)d_in[5];
    const float* W2 = (const float*)d_in[6];
    const float* b1 = (const float*)d_in[7];
    const float* b2 = (const float*)d_in[8];
    const int*   su = (const int*)d_in[9];
    const int*   oi = (const int*)d_in[10];
    const int*   ui = (const int*)d_in[11];
    float* out = (float*)d_out;

    // workspace carve (~85 MB)
    float* x      = (float*)d_ws;                    // 25.6 MB
    float* lie    = x + NODES * DD;                  // 25.6 MB
    int2*  bulk   = (int2*)(lie + NODES * DD);       // NBUCK*CAP int2 (28.6 MB)
    int*   gcur   = (int*)(bulk + NBUCK * CAP);      // NBUCK
    int*   starts = gcur + NBUCK + 1;                // NBUCK*SPB (5.2 MB)

    k_init_x<<<(NODES * DD / 4 + 255) / 256, 256, 0, stream>>>(eu, ei, x, gcur);
    k_gather<<<(3 * BB * 64 + 255) / 256, 256, 0, stream>>>(x, su, oi, ui, out, 0);

    k_place<<<NPB, 512, 0, stream>>>(edge_row, edge_col, edge_val, gcur, bulk);
    k_csr<<<NBUCK, 512, 0, stream>>>(gcur, bulk, starts);

    for (int l = 0; l < 3; ++l) {
        if (l == 1)
            k_cspmm<2><<<NBUCK, 1024, 0, stream>>>(starts, bulk, x, lie);
        else
            k_cspmm<5><<<NBUCK, 1024, 0, stream>>>(starts, bulk, x, lie);
        k_gemm<<<(NODES + 63) / 64, 256, 0, stream>>>(x, lie,
                                                      W1 + l * 4096, W2 + l * 4096,
                                                      b1 + l * 64,  b2 + l * 64);
        k_gather<<<(3 * BB * 64 + 255) / 256, 256, 0, stream>>>(x, su, oi, ui, out, l + 1);
    }
}

// Round 5
// 619.280 us; speedup vs baseline: 1.1858x; 1.0082x over previous
//
#include <hip/hip_runtime.h>

#define NN    60000
#define NODES 100000
#define DD    64
#define NNZ   3200000
#define BB    1024
#define NEG   0.2f
#define RPB   196                        // rows per bucket
#define NBUCK 511                        // ceil(NODES/RPB)
#define EPB   8192                       // edges per sort block
#define NPB   ((NNZ + EPB - 1) / EPB)    // 391
#define CAP   7000                       // bucket capacity (mean 6272, sd~79)
#define BCAP  7168                       // LDS edge capacity in k_csr
#define NSEG  13                         // column segments (col>>13), ~2 MB x-slice each
#define KEYN  (NSEG * RPB)               // 2548 sort keys per bucket
#define SPB   (KEYN + 1)                 // starts entries per bucket

// ---------------------------------------------------------------- init x = concat(eu, ei); also init gcur
__global__ __launch_bounds__(256) void k_init_x(const float* __restrict__ eu,
                                                const float* __restrict__ ei,
                                                float* __restrict__ x,
                                                int* __restrict__ gcur) {
    int i = blockIdx.x * 256 + threadIdx.x;          // float4 index
    if (i < NBUCK) gcur[i] = i * CAP;
    const int TOT = NODES * DD / 4;
    if (i >= TOT) return;
    const int UE = NN * DD / 4;
    float4 v = (i < UE) ? ((const float4*)eu)[i] : ((const float4*)ei)[i - UE];
    ((float4*)x)[i] = v;
}

// ---------------------------------------------------------------- bucket sort -> bulk
__global__ __launch_bounds__(512) void k_place(const int* __restrict__ row,
                                               const int* __restrict__ col,
                                               const float* __restrict__ val,
                                               int* __restrict__ gcur,
                                               int2* __restrict__ bulk) {
    __shared__ int rows_l[EPB];                // 32 KB
    __shared__ unsigned short perm[EPB];       // 16 KB
    __shared__ int h[NBUCK], bloc[NBUCK], bcur[NBUCK], gseg[NBUCK];
    __shared__ int sc[512];
    int t = threadIdx.x;
    if (t < NBUCK) h[t] = 0;
    __syncthreads();
    int base = blockIdx.x * EPB;
    int n = min(EPB, NNZ - base);
    for (int k = t; k < n; k += 512) {
        int r = row[base + k];
        rows_l[k] = r;
        atomicAdd(&h[r / RPB], 1);
    }
    __syncthreads();
    {
        int v = (t < NBUCK) ? h[t] : 0;
        sc[t] = v;
        __syncthreads();
        for (int off = 1; off < 512; off <<= 1) {
            int u = (t >= off) ? sc[t - off] : 0;
            __syncthreads();
            sc[t] += u;
            __syncthreads();
        }
        if (t < NBUCK) {
            int ex = sc[t] - v;
            bloc[t] = ex;
            bcur[t] = ex;
            gseg[t] = v ? atomicAdd(&gcur[t], v) : 0;
        }
    }
    __syncthreads();
    for (int k = t; k < n; k += 512) {
        int p = atomicAdd(&bcur[rows_l[k] / RPB], 1);
        perm[p] = (unsigned short)k;
    }
    __syncthreads();
    for (int j = t; j < n; j += 512) {
        int k = perm[j];
        int r = rows_l[k];
        int b = r / RPB;
        int addr = gseg[b] + (j - bloc[b]);
        bulk[addr] = make_int2(((r - b * RPB) << 17) | col[base + k],
                               __float_as_int(val[base + k]));
    }
}

// ---------------------------------------------------------------- per-bucket (colseg,row) sort
// in-place (keeps packed local-row bits); emit per-key span starts + sentinel
__global__ __launch_bounds__(512) void k_csr(const int* __restrict__ gcur,
                                             int2* __restrict__ bulk,
                                             int* __restrict__ starts) {
    __shared__ int2 eds[BCAP];                 // 56 KB
    __shared__ int cnt[KEYN], pos[KEYN];       // 20 KB
    __shared__ int part[512];
    int b = blockIdx.x, t = threadIdx.x;
    int lo = b * CAP;
    int n = gcur[b] - lo;
    for (int k = t; k < KEYN; k += 512) cnt[k] = 0;
    __syncthreads();
    for (int i = t; i < n; i += 512) {
        int2 ed = bulk[lo + i];
        eds[i] = ed;
        int lr = ed.x >> 17, c = ed.x & 0x1FFFF;
        atomicAdd(&cnt[(c >> 13) * RPB + lr], 1);
    }
    __syncthreads();
    // two-level exclusive scan over KEYN bins (5 bins/thread)
    int run = 0;
#pragma unroll
    for (int j = 0; j < 5; ++j) {
        int k = t * 5 + j;
        if (k < KEYN) { pos[k] = run; run += cnt[k]; }
    }
    part[t] = run;
    __syncthreads();
    for (int off = 1; off < 512; off <<= 1) {
        int u = (t >= off) ? part[t - off] : 0;
        __syncthreads();
        part[t] += u;
        __syncthreads();
    }
    int poff = part[t] - run;
#pragma unroll
    for (int j = 0; j < 5; ++j) {
        int k = t * 5 + j;
        if (k < KEYN) pos[k] += poff;
    }
    __syncthreads();
    for (int k = t; k < KEYN; k += 512) {
        starts[b * SPB + k] = lo + pos[k];
        cnt[k] = pos[k];                      // reuse as cursor
    }
    if (t == 0) starts[b * SPB + KEYN] = lo + n;
    __syncthreads();
    for (int i = t; i < n; i += 512) {
        int2 ed = eds[i];
        int lr = ed.x >> 17, c = ed.x & 0x1FFFF;
        int p = atomicAdd(&cnt[(c >> 13) * RPB + lr], 1);
        bulk[lo + p] = ed;                    // keep packed (lr<<17 | col)
    }
}

// ---------------------------------------------------------------- convoyed seg-major pull SpMM
// V2 (exact round-1 measured form, single-variant build): 16 lanes cooperatively
// fetch 16 edges with one dwordx2; v_readlane broadcasts each edge to SGPRs;
// the fully-unrolled batch issues all 16 x-gathers before any fma consumes one.
// s/e deliberately left as per-lane loads (the R4 readfirstlane preamble
// coincided with an ~85% slowdown of this same code path).
__global__ __launch_bounds__(1024) void k_cspmm(const int* __restrict__ starts,
                                                const int2* __restrict__ cv,
                                                const float* __restrict__ x,
                                                float* __restrict__ lie) {
    __shared__ float acc[RPB * DD];            // 49 KB
    int t = threadIdx.x, b = blockIdx.x;
    float4* av = (float4*)acc;
    for (int i = t; i < RPB * 16; i += 1024) av[i] = make_float4(0.f, 0.f, 0.f, 0.f);
    __syncthreads();
    int lane = t & 63;
    int wid = __builtin_amdgcn_readfirstlane(t >> 6);   // provably wave-uniform
    int r0 = (wid * RPB) >> 4;
    int r1 = ((wid + 1) * RPB) >> 4;
    int sb = b * SPB;
    for (int seg = 0; seg < NSEG; ++seg) {
        int s = starts[sb + seg * RPB + r0];
        int e = starts[sb + seg * RPB + r1];   // r1==RPB -> next seg's r0 / sentinel
        int cur = -1;
        float f = 0.f;
        for (int g = s; g < e; g += 16) {
            int rem = e - g;
            if (rem > 16) rem = 16;
            int idx = lane & 15;
            if (idx >= rem) idx = rem - 1;
            int2 my = cv[g + idx];             // one dwordx2 fetches 16 edges
            if (rem == 16) {
#pragma unroll
                for (int j = 0; j < 16; ++j) {
                    int sx = __builtin_amdgcn_readlane(my.x, j);
                    int sy = __builtin_amdgcn_readlane(my.y, j);
                    float xg = x[(sx & 0x1FFFF) * DD + lane];
                    int r = ((unsigned)sx) >> 17;
                    if (r != cur) {            // uniform branch
                        if (cur >= 0) acc[cur * DD + lane] += f;
                        cur = r; f = 0.f;
                    }
                    f = fmaf(__int_as_float(sy), xg, f);
                }
            } else {
                for (int j = 0; j < rem; ++j) {
                    int sx = __builtin_amdgcn_readlane(my.x, j);
                    int sy = __builtin_amdgcn_readlane(my.y, j);
                    float xg = x[(sx & 0x1FFFF) * DD + lane];
                    int r = ((unsigned)sx) >> 17;
                    if (r != cur) {
                        if (cur >= 0) acc[cur * DD + lane] += f;
                        cur = r; f = 0.f;
                    }
                    f = fmaf(__int_as_float(sy), xg, f);
                }
            }
        }
        if (cur >= 0) acc[cur * DD + lane] += f;
    }
    __syncthreads();
    int row0 = b * RPB;
    for (int i = t; i < RPB * 16; i += 1024) {
        int gr = row0 + (i >> 4);
        if (gr < NODES) ((float4*)lie)[gr * 16 + (i & 15)] = av[i];
    }
}

// ---------------------------------------------------------------- fused layer GEMM
__global__ __launch_bounds__(256) void k_gemm(float* __restrict__ x,
                                              const float* __restrict__ lie,
                                              const float* __restrict__ W1,
                                              const float* __restrict__ W2,
                                              const float* __restrict__ b1,
                                              const float* __restrict__ b2) {
    __shared__ float A1[64 * 64];
    __shared__ float A2[64 * 64];
    __shared__ float Ws1[64 * 64];
    __shared__ float Ws2[64 * 64];

    const int t = threadIdx.x;
    const int row0 = blockIdx.x * 64;

    {
        const float4* w1v = (const float4*)W1;
        const float4* w2v = (const float4*)W2;
        float4* s1v = (float4*)Ws1;
        float4* s2v = (float4*)Ws2;
#pragma unroll
        for (int q = 0; q < 4; ++q) {
            s1v[q * 256 + t] = w1v[q * 256 + t];
            s2v[q * 256 + t] = w2v[q * 256 + t];
        }
    }
#pragma unroll
    for (int q = 0; q < 4; ++q) {
        int f4 = q * 256 + t;
        int rl = f4 >> 4;
        int c4 = f4 & 15;
        int gr = row0 + rl;
        float4 lv = make_float4(0.f, 0.f, 0.f, 0.f);
        float4 xv = make_float4(0.f, 0.f, 0.f, 0.f);
        if (gr < NODES) {
            lv = *(const float4*)&lie[gr * DD + c4 * 4];
            xv = *(const float4*)&x[gr * DD + c4 * 4];
        }
        int sg = c4 ^ (rl & 15);
        ((float4*)A1)[rl * 16 + sg] = lv;
        ((float4*)A2)[rl * 16 + sg] = make_float4(lv.x * xv.x, lv.y * xv.y,
                                                  lv.z * xv.z, lv.w * xv.w);
    }
    __syncthreads();

    const int tx = t & 15;
    const int ty = t >> 4;
    float bs[4];
    {
        float4 bb1 = *(const float4*)&b1[tx * 4];
        float4 bb2 = *(const float4*)&b2[tx * 4];
        bs[0] = bb1.x + bb2.x; bs[1] = bb1.y + bb2.y;
        bs[2] = bb1.z + bb2.z; bs[3] = bb1.w + bb2.w;
    }
    float acc[4][4];
#pragma unroll
    for (int i = 0; i < 4; ++i)
#pragma unroll
        for (int j = 0; j < 4; ++j) acc[i][j] = bs[j];

    for (int k4 = 0; k4 < 16; ++k4) {
        float4 a1[4], a2[4];
#pragma unroll
        for (int i = 0; i < 4; ++i) {
            int r = ty * 4 + i;
            int sg = k4 ^ (r & 15);
            a1[i] = ((const float4*)A1)[r * 16 + sg];
            a2[i] = ((const float4*)A2)[r * 16 + sg];
        }
#pragma unroll
        for (int kk = 0; kk < 4; ++kk) {
            float4 w1 = ((const float4*)Ws1)[(k4 * 4 + kk) * 16 + tx];
            float4 w2 = ((const float4*)Ws2)[(k4 * 4 + kk) * 16 + tx];
#pragma unroll
            for (int i = 0; i < 4; ++i) {
                float av1 = (&a1[i].x)[kk];
                float av2 = (&a2[i].x)[kk];
                acc[i][0] = fmaf(av1, w1.x, fmaf(av2, w2.x, acc[i][0]));
                acc[i][1] = fmaf(av1, w1.y, fmaf(av2, w2.y, acc[i][1]));
                acc[i][2] = fmaf(av1, w1.z, fmaf(av2, w2.z, acc[i][2]));
                acc[i][3] = fmaf(av1, w1.w, fmaf(av2, w2.w, acc[i][3]));
            }
        }
    }
#pragma unroll
    for (int i = 0; i < 4; ++i) {
        int gr = row0 + ty * 4 + i;
        if (gr < NODES) {
            float4 o;
            o.x = acc[i][0] >= 0.f ? acc[i][0] : NEG * acc[i][0];
            o.y = acc[i][1] >= 0.f ? acc[i][1] : NEG * acc[i][1];
            o.z = acc[i][2] >= 0.f ? acc[i][2] : NEG * acc[i][2];
            o.w = acc[i][3] >= 0.f ? acc[i][3] : NEG * acc[i][3];
            *(float4*)&x[gr * DD + tx * 4] = o;
        }
    }
}

// ---------------------------------------------------------------- gather layer repr into output
__global__ __launch_bounds__(256) void k_gather(const float* __restrict__ x,
                                                const int* __restrict__ su,
                                                const int* __restrict__ oi,
                                                const int* __restrict__ ui,
                                                float* __restrict__ out, int layer) {
    int w    = (blockIdx.x * 256 + threadIdx.x) >> 6;
    int lane = threadIdx.x & 63;
    if (w >= 3 * BB) return;
    int g = w >> 10, b = w & 1023;
    int node = (g == 0) ? su[b] : (NN + ((g == 1) ? oi[b] : ui[b]));
    out[w * 256 + layer * 64 + lane] = x[node * DD + lane];
}

// ---------------------------------------------------------------- launch
extern "C" void kernel_launch(void* const* d_in, const int* in_sizes, int n_in,
                              void* d_out, int out_size, void* d_ws, size_t ws_size,
                              hipStream_t stream) {
    const int*   edge_row = (const int*)d_in[0];
    const int*   edge_col = (const int*)d_in[1];
    const float* edge_val = (const float*)d_in[2];
    const float* eu = (const float*)d_in[3];
    const float* ei = (const float*)d_in[4];
    const float* W1 = (const float*)d_in[5];
    const float* W2 = (const float*)d_in[6];
    const float* b1 = (const float*)d_in[7];
    const float* b2 = (const float*)d_in[8];
    const int*   su = (const int*)d_in[9];
    const int*   oi = (const int*)d_in[10];
    const int*   ui = (const int*)d_in[11];
    float* out = (float*)d_out;

    // workspace carve (~85 MB)
    float* x      = (float*)d_ws;                    // 25.6 MB
    float* lie    = x + NODES * DD;                  // 25.6 MB
    int2*  bulk   = (int2*)(lie + NODES * DD);       // NBUCK*CAP int2 (28.6 MB)
    int*   gcur   = (int*)(bulk + NBUCK * CAP);      // NBUCK
    int*   starts = gcur + NBUCK + 1;                // NBUCK*SPB (5.2 MB)

    k_init_x<<<(NODES * DD / 4 + 255) / 256, 256, 0, stream>>>(eu, ei, x, gcur);
    k_gather<<<(3 * BB * 64 + 255) / 256, 256, 0, stream>>>(x, su, oi, ui, out, 0);

    k_place<<<NPB, 512, 0, stream>>>(edge_row, edge_col, edge_val, gcur, bulk);
    k_csr<<<NBUCK, 512, 0, stream>>>(gcur, bulk, starts);

    for (int l = 0; l < 3; ++l) {
        k_cspmm<<<NBUCK, 1024, 0, stream>>>(starts, bulk, x, lie);
        k_gemm<<<(NODES + 63) / 64, 256, 0, stream>>>(x, lie,
                                                      W1 + l * 4096, W2 + l * 4096,
                                                      b1 + l * 64,  b2 + l * 64);
        k_gather<<<(3 * BB * 64 + 255) / 256, 256, 0, stream>>>(x, su, oi, ui, out, l + 1);
    }
}

// Round 6
// 573.121 us; speedup vs baseline: 1.2813x; 1.0805x over previous
//
#include <hip/hip_runtime.h>

#define NN    60000
#define NODES 100000
#define DD    64
#define NNZ   3200000
#define BB    1024
#define NEG   0.2f
#define RPB   196                        // rows per bucket
#define NBUCK 511                        // ceil(NODES/RPB)
#define EPB   8192                       // edges per sort block
#define NPB   ((NNZ + EPB - 1) / EPB)    // 391
#define CAP   7000                       // bucket capacity (mean 6272, sd~79)
#define BCAP  7168                       // LDS edge capacity in k_csr
#define NSEG  13                         // column segments (col>>13), ~2 MB x-slice each
#define KEYN  (NSEG * RPB)               // 2548 sort keys per bucket
#define SPB   (KEYN + 1)                 // starts entries per bucket

// ---------------------------------------------------------------- init x = concat(eu, ei); also init gcur
__global__ __launch_bounds__(256) void k_init_x(const float* __restrict__ eu,
                                                const float* __restrict__ ei,
                                                float* __restrict__ x,
                                                int* __restrict__ gcur) {
    int i = blockIdx.x * 256 + threadIdx.x;          // float4 index
    if (i < NBUCK) gcur[i] = i * CAP;
    const int TOT = NODES * DD / 4;
    if (i >= TOT) return;
    const int UE = NN * DD / 4;
    float4 v = (i < UE) ? ((const float4*)eu)[i] : ((const float4*)ei)[i - UE];
    ((float4*)x)[i] = v;
}

// ---------------------------------------------------------------- bucket sort -> bulk
__global__ __launch_bounds__(512) void k_place(const int* __restrict__ row,
                                               const int* __restrict__ col,
                                               const float* __restrict__ val,
                                               int* __restrict__ gcur,
                                               int2* __restrict__ bulk) {
    __shared__ int rows_l[EPB];                // 32 KB
    __shared__ unsigned short perm[EPB];       // 16 KB
    __shared__ int h[NBUCK], bloc[NBUCK], bcur[NBUCK], gseg[NBUCK];
    __shared__ int sc[512];
    int t = threadIdx.x;
    if (t < NBUCK) h[t] = 0;
    __syncthreads();
    int base = blockIdx.x * EPB;
    int n = min(EPB, NNZ - base);
    for (int k = t; k < n; k += 512) {
        int r = row[base + k];
        rows_l[k] = r;
        atomicAdd(&h[r / RPB], 1);
    }
    __syncthreads();
    {
        int v = (t < NBUCK) ? h[t] : 0;
        sc[t] = v;
        __syncthreads();
        for (int off = 1; off < 512; off <<= 1) {
            int u = (t >= off) ? sc[t - off] : 0;
            __syncthreads();
            sc[t] += u;
            __syncthreads();
        }
        if (t < NBUCK) {
            int ex = sc[t] - v;
            bloc[t] = ex;
            bcur[t] = ex;
            gseg[t] = v ? atomicAdd(&gcur[t], v) : 0;
        }
    }
    __syncthreads();
    for (int k = t; k < n; k += 512) {
        int p = atomicAdd(&bcur[rows_l[k] / RPB], 1);
        perm[p] = (unsigned short)k;
    }
    __syncthreads();
    for (int j = t; j < n; j += 512) {
        int k = perm[j];
        int r = rows_l[k];
        int b = r / RPB;
        int addr = gseg[b] + (j - bloc[b]);
        bulk[addr] = make_int2(((r - b * RPB) << 17) | col[base + k],
                               __float_as_int(val[base + k]));
    }
}

// ---------------------------------------------------------------- per-bucket (colseg,row) sort
// in-place (keeps packed local-row bits); emit per-key span starts + sentinel
__global__ __launch_bounds__(512) void k_csr(const int* __restrict__ gcur,
                                             int2* __restrict__ bulk,
                                             int* __restrict__ starts) {
    __shared__ int2 eds[BCAP];                 // 56 KB
    __shared__ int cnt[KEYN], pos[KEYN];       // 20 KB
    __shared__ int part[512];
    int b = blockIdx.x, t = threadIdx.x;
    int lo = b * CAP;
    int n = gcur[b] - lo;
    for (int k = t; k < KEYN; k += 512) cnt[k] = 0;
    __syncthreads();
    for (int i = t; i < n; i += 512) {
        int2 ed = bulk[lo + i];
        eds[i] = ed;
        int lr = ed.x >> 17, c = ed.x & 0x1FFFF;
        atomicAdd(&cnt[(c >> 13) * RPB + lr], 1);
    }
    __syncthreads();
    // two-level exclusive scan over KEYN bins (5 bins/thread)
    int run = 0;
#pragma unroll
    for (int j = 0; j < 5; ++j) {
        int k = t * 5 + j;
        if (k < KEYN) { pos[k] = run; run += cnt[k]; }
    }
    part[t] = run;
    __syncthreads();
    for (int off = 1; off < 512; off <<= 1) {
        int u = (t >= off) ? part[t - off] : 0;
        __syncthreads();
        part[t] += u;
        __syncthreads();
    }
    int poff = part[t] - run;
#pragma unroll
    for (int j = 0; j < 5; ++j) {
        int k = t * 5 + j;
        if (k < KEYN) pos[k] += poff;
    }
    __syncthreads();
    for (int k = t; k < KEYN; k += 512) {
        starts[b * SPB + k] = lo + pos[k];
        cnt[k] = pos[k];                      // reuse as cursor
    }
    if (t == 0) starts[b * SPB + KEYN] = lo + n;
    __syncthreads();
    for (int i = t; i < n; i += 512) {
        int2 ed = eds[i];
        int lr = ed.x >> 17, c = ed.x & 0x1FFFF;
        int p = atomicAdd(&cnt[(c >> 13) * RPB + lr], 1);
        bulk[lo + p] = ed;                    // keep packed (lr<<17 | col)
    }
}

// ---------------------------------------------------------------- convoyed seg-major pull SpMM
// V1 (the R1-inferred ~85-90us winner): readfirstlane(wid) makes s/e/g uniform
// -> scalar loop control + uniform-address broadcast cv loads; per-lane 8-deep
// blocks keep 8 gathers in flight.
// BLK=16 arm: depth-16 blocks with index-clamped zero-value tail padding --
// no serial tail, 16 gathers in flight at each vmcnt wait. Clamped pad edges
// carry the last edge's row (no spurious flush) and vv=0 (no contribution).
template <int BLK>
__global__ __launch_bounds__(1024) void k_cspmm(const int* __restrict__ starts,
                                                const int2* __restrict__ cv,
                                                const float* __restrict__ x,
                                                float* __restrict__ lie) {
    __shared__ float acc[RPB * DD];            // 49 KB
    int t = threadIdx.x, b = blockIdx.x;
    float4* av = (float4*)acc;
    for (int i = t; i < RPB * 16; i += 1024) av[i] = make_float4(0.f, 0.f, 0.f, 0.f);
    __syncthreads();
    int lane = t & 63;
    int wid = __builtin_amdgcn_readfirstlane(t >> 6);   // provably wave-uniform
    int r0 = (wid * RPB) >> 4;
    int r1 = ((wid + 1) * RPB) >> 4;
    int sb = b * SPB;
    for (int seg = 0; seg < NSEG; ++seg) {
        int s = starts[sb + seg * RPB + r0];
        int e = starts[sb + seg * RPB + r1];   // r1==RPB -> next seg's r0 / sentinel
        int cur = -1;
        float f = 0.f;
        if constexpr (BLK == 8) {
            // exact R1 V1 body
            int g = s;
            for (; g + 8 <= e; g += 8) {
                int2 ee[8];
#pragma unroll
                for (int j = 0; j < 8; ++j) ee[j] = cv[g + j];
                float xv[8];
#pragma unroll
                for (int j = 0; j < 8; ++j) xv[j] = x[(ee[j].x & 0x1FFFF) * DD + lane];
#pragma unroll
                for (int j = 0; j < 8; ++j) {
                    int r = ee[j].x >> 17;
                    if (r != cur) {             // wave-uniform branch
                        if (cur >= 0) acc[cur * DD + lane] += f;
                        cur = r; f = 0.f;
                    }
                    f = fmaf(__int_as_float(ee[j].y), xv[j], f);
                }
            }
            for (; g < e; ++g) {
                int2 ed = cv[g];
                float xg = x[(ed.x & 0x1FFFF) * DD + lane];
                int r = ed.x >> 17;
                if (r != cur) {
                    if (cur >= 0) acc[cur * DD + lane] += f;
                    cur = r; f = 0.f;
                }
                f = fmaf(__int_as_float(ed.y), xg, f);
            }
        } else {
            for (int g = s; g < e; g += BLK) {
                int2 ee[BLK];
#pragma unroll
                for (int j = 0; j < BLK; ++j) {
                    int idx = (g + j < e) ? g + j : e - 1;   // uniform clamp
                    ee[j] = cv[idx];
                }
                float xv[BLK];
#pragma unroll
                for (int j = 0; j < BLK; ++j) xv[j] = x[(ee[j].x & 0x1FFFF) * DD + lane];
#pragma unroll
                for (int j = 0; j < BLK; ++j) {
                    int r = ee[j].x >> 17;
                    if (r != cur) {             // wave-uniform branch
                        if (cur >= 0) acc[cur * DD + lane] += f;
                        cur = r; f = 0.f;
                    }
                    float vv = (g + j < e) ? __int_as_float(ee[j].y) : 0.f;
                    f = fmaf(vv, xv[j], f);
                }
            }
        }
        if (cur >= 0) acc[cur * DD + lane] += f;
    }
    __syncthreads();
    int row0 = b * RPB;
    for (int i = t; i < RPB * 16; i += 1024) {
        int gr = row0 + (i >> 4);
        if (gr < NODES) ((float4*)lie)[gr * 16 + (i & 15)] = av[i];
    }
}

// ---------------------------------------------------------------- fused layer GEMM
__global__ __launch_bounds__(256) void k_gemm(float* __restrict__ x,
                                              const float* __restrict__ lie,
                                              const float* __restrict__ W1,
                                              const float* __restrict__ W2,
                                              const float* __restrict__ b1,
                                              const float* __restrict__ b2) {
    __shared__ float A1[64 * 64];
    __shared__ float A2[64 * 64];
    __shared__ float Ws1[64 * 64];
    __shared__ float Ws2[64 * 64];

    const int t = threadIdx.x;
    const int row0 = blockIdx.x * 64;

    {
        const float4* w1v = (const float4*)W1;
        const float4* w2v = (const float4*)W2;
        float4* s1v = (float4*)Ws1;
        float4* s2v = (float4*)Ws2;
#pragma unroll
        for (int q = 0; q < 4; ++q) {
            s1v[q * 256 + t] = w1v[q * 256 + t];
            s2v[q * 256 + t] = w2v[q * 256 + t];
        }
    }
#pragma unroll
    for (int q = 0; q < 4; ++q) {
        int f4 = q * 256 + t;
        int rl = f4 >> 4;
        int c4 = f4 & 15;
        int gr = row0 + rl;
        float4 lv = make_float4(0.f, 0.f, 0.f, 0.f);
        float4 xv = make_float4(0.f, 0.f, 0.f, 0.f);
        if (gr < NODES) {
            lv = *(const float4*)&lie[gr * DD + c4 * 4];
            xv = *(const float4*)&x[gr * DD + c4 * 4];
        }
        int sg = c4 ^ (rl & 15);
        ((float4*)A1)[rl * 16 + sg] = lv;
        ((float4*)A2)[rl * 16 + sg] = make_float4(lv.x * xv.x, lv.y * xv.y,
                                                  lv.z * xv.z, lv.w * xv.w);
    }
    __syncthreads();

    const int tx = t & 15;
    const int ty = t >> 4;
    float bs[4];
    {
        float4 bb1 = *(const float4*)&b1[tx * 4];
        float4 bb2 = *(const float4*)&b2[tx * 4];
        bs[0] = bb1.x + bb2.x; bs[1] = bb1.y + bb2.y;
        bs[2] = bb1.z + bb2.z; bs[3] = bb1.w + bb2.w;
    }
    float acc[4][4];
#pragma unroll
    for (int i = 0; i < 4; ++i)
#pragma unroll
        for (int j = 0; j < 4; ++j) acc[i][j] = bs[j];

    for (int k4 = 0; k4 < 16; ++k4) {
        float4 a1[4], a2[4];
#pragma unroll
        for (int i = 0; i < 4; ++i) {
            int r = ty * 4 + i;
            int sg = k4 ^ (r & 15);
            a1[i] = ((const float4*)A1)[r * 16 + sg];
            a2[i] = ((const float4*)A2)[r * 16 + sg];
        }
#pragma unroll
        for (int kk = 0; kk < 4; ++kk) {
            float4 w1 = ((const float4*)Ws1)[(k4 * 4 + kk) * 16 + tx];
            float4 w2 = ((const float4*)Ws2)[(k4 * 4 + kk) * 16 + tx];
#pragma unroll
            for (int i = 0; i < 4; ++i) {
                float av1 = (&a1[i].x)[kk];
                float av2 = (&a2[i].x)[kk];
                acc[i][0] = fmaf(av1, w1.x, fmaf(av2, w2.x, acc[i][0]));
                acc[i][1] = fmaf(av1, w1.y, fmaf(av2, w2.y, acc[i][1]));
                acc[i][2] = fmaf(av1, w1.z, fmaf(av2, w2.z, acc[i][2]));
                acc[i][3] = fmaf(av1, w1.w, fmaf(av2, w2.w, acc[i][3]));
            }
        }
    }
#pragma unroll
    for (int i = 0; i < 4; ++i) {
        int gr = row0 + ty * 4 + i;
        if (gr < NODES) {
            float4 o;
            o.x = acc[i][0] >= 0.f ? acc[i][0] : NEG * acc[i][0];
            o.y = acc[i][1] >= 0.f ? acc[i][1] : NEG * acc[i][1];
            o.z = acc[i][2] >= 0.f ? acc[i][2] : NEG * acc[i][2];
            o.w = acc[i][3] >= 0.f ? acc[i][3] : NEG * acc[i][3];
            *(float4*)&x[gr * DD + tx * 4] = o;
        }
    }
}

// ---------------------------------------------------------------- gather layer repr into output
__global__ __launch_bounds__(256) void k_gather(const float* __restrict__ x,
                                                const int* __restrict__ su,
                                                const int* __restrict__ oi,
                                                const int* __restrict__ ui,
                                                float* __restrict__ out, int layer) {
    int w    = (blockIdx.x * 256 + threadIdx.x) >> 6;
    int lane = threadIdx.x & 63;
    if (w >= 3 * BB) return;
    int g = w >> 10, b = w & 1023;
    int node = (g == 0) ? su[b] : (NN + ((g == 1) ? oi[b] : ui[b]));
    out[w * 256 + layer * 64 + lane] = x[node * DD + lane];
}

// ---------------------------------------------------------------- launch
extern "C" void kernel_launch(void* const* d_in, const int* in_sizes, int n_in,
                              void* d_out, int out_size, void* d_ws, size_t ws_size,
                              hipStream_t stream) {
    const int*   edge_row = (const int*)d_in[0];
    const int*   edge_col = (const int*)d_in[1];
    const float* edge_val = (const float*)d_in[2];
    const float* eu = (const float*)d_in[3];
    const float* ei = (const float*)d_in[4];
    const float* W1 = (const float*)d_in[5];
    const float* W2 = (const float*)d_in[6];
    const float* b1 = (const float*)d_in[7];
    const float* b2 = (const float*)d_in[8];
    const int*   su = (const int*)d_in[9];
    const int*   oi = (const int*)d_in[10];
    const int*   ui = (const int*)d_in[11];
    float* out = (float*)d_out;

    // workspace carve (~85 MB)
    float* x      = (float*)d_ws;                    // 25.6 MB
    float* lie    = x + NODES * DD;                  // 25.6 MB
    int2*  bulk   = (int2*)(lie + NODES * DD);       // NBUCK*CAP int2 (28.6 MB)
    int*   gcur   = (int*)(bulk + NBUCK * CAP);      // NBUCK
    int*   starts = gcur + NBUCK + 1;                // NBUCK*SPB (5.2 MB)

    k_init_x<<<(NODES * DD / 4 + 255) / 256, 256, 0, stream>>>(eu, ei, x, gcur);
    k_gather<<<(3 * BB * 64 + 255) / 256, 256, 0, stream>>>(x, su, oi, ui, out, 0);

    k_place<<<NPB, 512, 0, stream>>>(edge_row, edge_col, edge_val, gcur, bulk);
    k_csr<<<NBUCK, 512, 0, stream>>>(gcur, bulk, starts);

    for (int l = 0; l < 3; ++l) {
        if (l == 1)
            k_cspmm<16><<<NBUCK, 1024, 0, stream>>>(starts, bulk, x, lie);
        else
            k_cspmm<8><<<NBUCK, 1024, 0, stream>>>(starts, bulk, x, lie);
        k_gemm<<<(NODES + 63) / 64, 256, 0, stream>>>(x, lie,
                                                      W1 + l * 4096, W2 + l * 4096,
                                                      b1 + l * 64,  b2 + l * 64);
        k_gather<<<(3 * BB * 64 + 255) / 256, 256, 0, stream>>>(x, su, oi, ui, out, l + 1);
    }
}